// Round 1
// baseline (177318.774 us; speedup 1.0000x reference)
//
#include <hip/hip_runtime.h>
#include <math.h>

// ---------------------------------------------------------------------------
// AttentionalLSTM  (B=128, T=256, D_IN=512, H=1024)
// Round 0: correctness-first fp32 baseline.
//   per step: gates GEMM -> LSTM cell -> q GEMM -> attention -> out GEMM(tanh)
// ---------------------------------------------------------------------------

#define B_  128
#define T_  256
#define DIN 512
#define H_  1024

// --------------------------- bias sum --------------------------------------
__global__ void bias_sum_k(const float* __restrict__ a, const float* __restrict__ b,
                           float* __restrict__ o, int n) {
    int i = blockIdx.x * blockDim.x + threadIdx.x;
    if (i < n) o[i] = a[i] + b[i];
}

// --------------------------- mask dtype sniffer ----------------------------
// bool arrays arrive as 1-byte elements; int32 as 4-byte. Reading the buffer
// as int32 words: a random 0/1 byte stream gives words outside {0,1} almost
// surely, while a real int32 0/1 mask stays within {0,1}.
__global__ void detect_mask_k(const int* __restrict__ m, int nwords, int* __restrict__ flag) {
    __shared__ int bad;
    if (threadIdx.x == 0) bad = 0;
    __syncthreads();
    for (int i = threadIdx.x; i < nwords; i += blockDim.x) {
        unsigned v = (unsigned)m[i];
        if (v > 1u) bad = 1;   // benign race, all writers store 1
    }
    __syncthreads();
    if (threadIdx.x == 0) flag[0] = bad ? 0 : 1;  // 1 => int32 mask, 0 => u8 mask
}

// --------------------------- tiled fp32 GEMM -------------------------------
// C[M,N] = [A1 | A2] @ [W1 | W2]^T (+bias) (+tanh epilogue, up to 3 dests)
// A1: [M,K1] rows stride lda1; A2: [M,K2] rows stride lda2 (may be null, K2=0)
// W1 rows: W1[n*ldw1 + k], k in [0,K1); W2 rows: W2[n*ldw2 + k], k in [0,K2)
template<int EPI>
__global__ __launch_bounds__(256)
void gemm_k(const float* __restrict__ A1, int lda1, int K1,
            const float* __restrict__ A2, int lda2, int K2,
            const float* __restrict__ W1, int ldw1,
            const float* __restrict__ W2, int ldw2,
            const float* __restrict__ bias,
            float* __restrict__ C0, int ldc0,
            float* __restrict__ C1, int ldc1,
            float* __restrict__ C2, int ldc2)
{
    constexpr int BM = 64, BN = 32, BK = 32, TM = 2, TN = 4;
    __shared__ float As[BK][BM + 2];
    __shared__ float Bs[BK][BN + 4];
    const int bn = blockIdx.x * BN;
    const int bm = blockIdx.y * BM;
    const int tid = threadIdx.x;
    const int tx = tid & 7;     // 8 threads along N
    const int ty = tid >> 3;    // 32 threads along M

    float acc[TM][TN] = {};
    const int K = K1 + K2;

    for (int kb = 0; kb < K; kb += BK) {
        const float* A; const float* W; int lda, ldw, kk;
        if (kb < K1) { A = A1; lda = lda1; W = W1; ldw = ldw1; kk = kb; }
        else         { A = A2; lda = lda2; W = W2; ldw = ldw2; kk = kb - K1; }

        #pragma unroll
        for (int i = 0; i < (BM * BK) / 256; ++i) {      // 8 iters
            int li = tid + i * 256;
            int m = li >> 5, k = li & 31;
            As[k][m] = A[(size_t)(bm + m) * lda + kk + k];
        }
        #pragma unroll
        for (int i = 0; i < (BN * BK) / 256; ++i) {      // 4 iters
            int li = tid + i * 256;
            int n = li >> 5, k = li & 31;
            Bs[k][n] = W[(size_t)(bn + n) * ldw + kk + k];
        }
        __syncthreads();

        #pragma unroll 8
        for (int k = 0; k < BK; ++k) {
            float ra[TM], rb[TN];
            #pragma unroll
            for (int i = 0; i < TM; ++i) ra[i] = As[k][ty * TM + i];
            #pragma unroll
            for (int j = 0; j < TN; ++j) rb[j] = Bs[k][tx * TN + j];
            #pragma unroll
            for (int i = 0; i < TM; ++i)
                #pragma unroll
                for (int j = 0; j < TN; ++j)
                    acc[i][j] += ra[i] * rb[j];
        }
        __syncthreads();
    }

    #pragma unroll
    for (int i = 0; i < TM; ++i) {
        int m = bm + ty * TM + i;
        #pragma unroll
        for (int j = 0; j < TN; ++j) {
            int n = bn + tx * TN + j;
            float v = acc[i][j];
            if (bias) v += bias[n];
            if (EPI == 1) v = tanhf(v);
            C0[(size_t)m * ldc0 + n] = v;
            if (EPI == 1) {
                C1[(size_t)m * ldc1 + n] = v;
                if (C2) C2[(size_t)m * ldc2 + n] = v;
            }
        }
    }
}

// --------------------------- LSTM cell -------------------------------------
__device__ __forceinline__ float sigmoidf_(float x) { return 1.f / (1.f + expf(-x)); }

__global__ __launch_bounds__(256)
void cell_k(const float* __restrict__ gates, const float* __restrict__ cprev,
            float* __restrict__ hy, float* __restrict__ cy, float* __restrict__ cextra)
{
    int idx = blockIdx.x * 256 + threadIdx.x;       // over B*H
    int m = idx >> 10;                               // H = 1024
    int j = idx & 1023;
    const float* g = gates + ((size_t)m << 12);      // 4H = 4096
    float ig = g[j], fg = g[1024 + j], gg = g[2048 + j], og = g[3072 + j];
    float c = sigmoidf_(fg) * cprev[idx] + sigmoidf_(ig) * tanhf(gg);
    float h = sigmoidf_(og) * tanhf(c);
    cy[idx] = c;
    hy[idx] = h;
    if (cextra) cextra[idx] = c;
}

// --------------------------- attention -------------------------------------
// one block per batch element: scores -> masked softmax -> weighted ctx
__global__ __launch_bounds__(256)
void attn_k(const float* __restrict__ ctx, const float* __restrict__ q,
            const void* __restrict__ maskp, const int* __restrict__ maskmode,
            float* __restrict__ wctx)
{
    constexpr int L = T_, H = H_;
    int b = blockIdx.x;
    const float* cb = ctx + (size_t)b * L * H;
    __shared__ float sq[H];
    __shared__ float sc[L];
    __shared__ float red[256];
    int tid = threadIdx.x;
    for (int k = tid; k < H; k += 256) sq[k] = q[b * H + k];
    int mode = maskmode[0];
    __syncthreads();

    int wave = tid >> 6, lane = tid & 63;
    for (int l = wave; l < L; l += 4) {
        float s = 0.f;
        for (int k = lane; k < H; k += 64) s += cb[(size_t)l * H + k] * sq[k];
        #pragma unroll
        for (int off = 32; off; off >>= 1) s += __shfl_down(s, off);
        if (lane == 0) {
            bool msk = mode ? (((const int*)maskp)[b * L + l] != 0)
                            : (((const unsigned char*)maskp)[b * L + l] != 0);
            sc[l] = msk ? -INFINITY : s;
        }
    }
    __syncthreads();

    float v = sc[tid];
    red[tid] = v; __syncthreads();
    for (int s = 128; s > 0; s >>= 1) { if (tid < s) red[tid] = fmaxf(red[tid], red[tid + s]); __syncthreads(); }
    float mx = red[0]; __syncthreads();
    float ex = expf(v - mx);                 // -inf -> 0
    red[tid] = ex; __syncthreads();
    for (int s = 128; s > 0; s >>= 1) { if (tid < s) red[tid] += red[tid + s]; __syncthreads(); }
    float sum = red[0];
    sc[tid] = ex / sum;
    __syncthreads();

    for (int k = tid; k < H; k += 256) {
        float a = 0.f;
        #pragma unroll 4
        for (int l = 0; l < L; ++l) a += sc[l] * cb[(size_t)l * H + k];
        wctx[b * H + k] = a;
    }
}

// --------------------------- launcher --------------------------------------
extern "C" void kernel_launch(void* const* d_in, const int* in_sizes, int n_in,
                              void* d_out, int out_size, void* d_ws, size_t ws_size,
                              hipStream_t stream)
{
    const float* input  = (const float*)d_in[0];
    const float* h0     = (const float*)d_in[1];
    const float* c0     = (const float*)d_in[2];
    const float* ctx    = (const float*)d_in[3];
    const void*  srcmask= d_in[4];
    const float* W_ih   = (const float*)d_in[5];
    const float* W_hh   = (const float*)d_in[6];
    const float* b_ih   = (const float*)d_in[7];
    const float* b_hh   = (const float*)d_in[8];
    const float* W_attn = (const float*)d_in[9];
    const float* W_out  = (const float*)d_in[10];

    constexpr int B = B_, T = T_, D = DIN, H = H_;
    float* ws     = (float*)d_ws;
    float* bsum   = ws;                   // 4H
    float* gates  = bsum + 4 * H;         // B*4H
    float* hbuf   = gates + (size_t)B * 4 * H;
    float* hybuf  = hbuf + (size_t)B * H;
    float* cbuf   = hybuf + (size_t)B * H;
    float* qbuf   = cbuf + (size_t)B * H;
    float* wctxb  = qbuf + (size_t)B * H;
    int*   mflag  = (int*)(wctxb + (size_t)B * H);

    float* out = (float*)d_out;
    float* hf_dst = out + (size_t)B * T * H;           // [B,H]
    float* cf_dst = hf_dst + (size_t)B * H;            // [B,H]

    bias_sum_k<<<dim3((4 * H + 255) / 256), dim3(256), 0, stream>>>(b_ih, b_hh, bsum, 4 * H);
    detect_mask_k<<<dim3(1), dim3(256), 0, stream>>>((const int*)srcmask, (B * T) / 4, mflag);

    dim3 blk(256);
    dim3 grid_g(4 * H / 32, B / 64);   // gates: N=4096
    dim3 grid_h(H / 32, B / 64);       // q / out: N=1024

    for (int t = 0; t < T; ++t) {
        const float* hprev = t ? hbuf : h0;
        const float* cprev = t ? cbuf : c0;

        // gates = [x_t | h] @ [W_ih | W_hh]^T + bsum
        gemm_k<0><<<grid_g, blk, 0, stream>>>(
            input + (size_t)t * D, T * D, D,
            hprev, H, H,
            W_ih, D, W_hh, H,
            bsum,
            gates, 4 * H, nullptr, 0, nullptr, 0);

        // LSTM cell
        cell_k<<<dim3(B * H / 256), blk, 0, stream>>>(
            gates, cprev, hybuf, cbuf, (t == T - 1) ? cf_dst : nullptr);

        // q = hy @ W_attn^T
        gemm_k<0><<<grid_h, blk, 0, stream>>>(
            hybuf, H, H,
            nullptr, 0, 0,
            W_attn, H, nullptr, 0,
            nullptr,
            qbuf, H, nullptr, 0, nullptr, 0);

        // attention
        attn_k<<<dim3(B), blk, 0, stream>>>(ctx, qbuf, srcmask, mflag, wctxb);

        // h_tilde = tanh([wctx | hy] @ W_out^T) -> hbuf, output[:,t,:], (h_f)
        gemm_k<1><<<grid_h, blk, 0, stream>>>(
            wctxb, H, H,
            hybuf, H, H,
            W_out, 2 * H, W_out + H, 2 * H,
            nullptr,
            hbuf, H,
            out + (size_t)t * H, T * H,
            (t == T - 1) ? hf_dst : nullptr, H);
    }
}

// Round 3
// 45617.072 us; speedup vs baseline: 3.8871x; 3.8871x over previous
//
#include <hip/hip_runtime.h>
#include <hip/hip_bf16.h>
#include <math.h>

#define B_  128
#define T_  256
#define DIN 512
#define H_  1024

typedef __attribute__((ext_vector_type(8))) short bf16x8;
typedef __attribute__((ext_vector_type(4))) float f32x4;

#define GLD_LDS16(gsrc, ldst) \
  __builtin_amdgcn_global_load_lds((const __attribute__((address_space(1))) void*)(gsrc), \
                                   (__attribute__((address_space(3))) void*)(ldst), 16, 0, 0)

__device__ __forceinline__ void split_bf16(float v, __hip_bfloat16* hi, __hip_bfloat16* lo) {
    __hip_bfloat16 h = __float2bfloat16(v);
    *hi = h;
    *lo = __float2bfloat16(v - __bfloat162float(h));
}

// --------------------------- small utility kernels -------------------------
__global__ void bias_sum_k(const float* __restrict__ a, const float* __restrict__ b,
                           float* __restrict__ o, int n) {
    int i = blockIdx.x * blockDim.x + threadIdx.x;
    if (i < n) o[i] = a[i] + b[i];
}

__global__ void detect_mask_k(const int* __restrict__ m, int nwords, int* __restrict__ flag) {
    __shared__ int bad;
    if (threadIdx.x == 0) bad = 0;
    __syncthreads();
    for (int i = threadIdx.x; i < nwords; i += blockDim.x) {
        unsigned v = (unsigned)m[i];
        if (v > 1u) bad = 1;
    }
    __syncthreads();
    if (threadIdx.x == 0) flag[0] = bad ? 0 : 1;  // 1 => int32 mask, 0 => u8 mask
}

__global__ void cvt_split_k(const float* __restrict__ s, __hip_bfloat16* __restrict__ hi,
                            __hip_bfloat16* __restrict__ lo, int n) {
    int i = blockIdx.x * 256 + threadIdx.x;
    if (i < n) split_bf16(s[i], hi + i, lo + i);
}

// combined [W_ih | W_hh] -> bf16 hi/lo [4096][1536]
__global__ void wg_split_k(const float* __restrict__ Wih, const float* __restrict__ Whh,
                           __hip_bfloat16* __restrict__ Wh, __hip_bfloat16* __restrict__ Wl) {
    int i = blockIdx.x * 256 + threadIdx.x;           // over 4096*1536
    int n = i / 1536, c = i - n * 1536;
    float v = (c < DIN) ? Wih[n * DIN + c] : Whh[n * H_ + (c - DIN)];
    split_bf16(v, Wh + i, Wl + i);
}

// x_t slice [128][512] fp32 -> hi/lo bf16
__device__ __forceinline__ void cvtx_body(int i, const float* __restrict__ xsrc,
                                          __hip_bfloat16* __restrict__ xh,
                                          __hip_bfloat16* __restrict__ xl) {
    int b = i >> 9, c = i & 511;
    split_bf16(xsrc[(size_t)b * (T_ * DIN) + c], xh + i, xl + i);
}

__global__ void cvtx_k(const float* __restrict__ xsrc, __hip_bfloat16* __restrict__ xh,
                       __hip_bfloat16* __restrict__ xl) {
    cvtx_body(blockIdx.x * 256 + threadIdx.x, xsrc, xh, xl);
}

// --------------------------- split-bf16 MFMA GEMM --------------------------
// C[128,N] = (Ah+Al)[128,K] @ (Wh+Wl)[N,K]^T  via 3 planes:
//   plane 0: Ah@Wh   plane 1: Al@Wh   plane 2: Ah@Wl
// A = [A1 (K1 cols) | A2]. BM=128, BK=64, 256 thr, dbuf LDS, swizzled source.
// EPI 0: C = acc + bias    EPI 1: C = acc
// EPI 2: v=tanh(acc): (Cbh,Cbl)=split(v) recur, C2=v out slice, C3?=v h_f
template<int BN, int WROWS, int WCOLS, int KT0, int EPI>
__global__ __launch_bounds__(256)
void mfma_gemm_k(const __hip_bfloat16* __restrict__ A1h, const __hip_bfloat16* __restrict__ A1l,
                 long lda1, int K1,
                 const __hip_bfloat16* __restrict__ A2h, const __hip_bfloat16* __restrict__ A2l,
                 long lda2,
                 const __hip_bfloat16* __restrict__ Wh, const __hip_bfloat16* __restrict__ Wl,
                 long ldw,
                 const float* __restrict__ bias,
                 float* __restrict__ C, long ldc,
                 __hip_bfloat16* __restrict__ Cbh, __hip_bfloat16* __restrict__ Cbl, long ldcb,
                 float* __restrict__ C2, long ldc2,
                 float* __restrict__ C3)
{
    constexpr int BM = 128, BK = 64;
    constexpr int WM = BM / WROWS, WN = BN / WCOLS;
    constexpr int FM = WM / 16, FN = WN / 16;
    constexpr int ABYTES = BM * BK * 2, BBYTES = BN * BK * 2;
    constexpr int BUFB = ABYTES + BBYTES;
    constexpr int ACHUNKS = BM * (BK / 8);
    constexpr int BCHUNKS = BN * (BK / 8);
    constexpr int KTILES = 3 * KT0;

    __shared__ __attribute__((aligned(16))) char lds[BUFB * 2];
    const int tid = threadIdx.x;
    const int l = tid & 63, w = tid >> 6;
    const int n0 = blockIdx.x * BN;
    const int wm = (w / WCOLS) * WM, wn = (w % WCOLS) * WN;

    auto stage = [&](int buf, int kt) {
        const int p  = (kt >= 2 * KT0) ? 2 : ((kt >= KT0) ? 1 : 0);
        const int kk = kt - p * KT0;
        const __hip_bfloat16* A1 = (p == 1) ? A1l : A1h;
        const __hip_bfloat16* A2 = (p == 1) ? A2l : A2h;
        const __hip_bfloat16* Wp = (p == 2) ? Wl  : Wh;
        char* base = lds + buf * BUFB;
        #pragma unroll
        for (int j = 0; j < ACHUNKS / 256; ++j) {
            int c = j * 256 + tid;
            int row = c >> 3, slot = c & 7;
            int e = kk * BK + ((slot ^ (row & 7)) << 3);
            const __hip_bfloat16* src = (e < K1) ? (A1 + (long)row * lda1 + e)
                                                 : (A2 + (long)row * lda2 + (e - K1));
            char* ldsb = base + ((j * 256 + (tid & 192)) << 4);
            GLD_LDS16(src, ldsb);
        }
        constexpr int BITER = (BCHUNKS + 255) / 256;
        #pragma unroll
        for (int j = 0; j < BITER; ++j) {
            int c = j * 256 + tid;
            if (BCHUNKS >= (j + 1) * 256 || c < BCHUNKS) {
                int row = c >> 3, slot = c & 7;
                const __hip_bfloat16* src = Wp + (long)(n0 + row) * ldw + kk * BK + ((slot ^ (row & 7)) << 3);
                char* ldsb = base + ABYTES + ((j * 256 + (tid & 192)) << 4);
                GLD_LDS16(src, ldsb);
            }
        }
    };

    f32x4 acc[FM][FN] = {};

    stage(0, 0);
    asm volatile("s_waitcnt vmcnt(0)" ::: "memory");
    __syncthreads();

    for (int kt = 0; kt < KTILES; ++kt) {
        if (kt + 1 < KTILES) stage((kt + 1) & 1, kt + 1);
        const char* base = lds + (kt & 1) * BUFB;

        bf16x8 af[FM][2], bfr[FN][2];
        #pragma unroll
        for (int ks = 0; ks < 2; ++ks) {
            #pragma unroll
            for (int mi = 0; mi < FM; ++mi) {
                int row = wm + mi * 16 + (l & 15);
                int slot = (l >> 4) + ks * 4;
                af[mi][ks] = *(const bf16x8*)(base + row * 128 + ((slot ^ (row & 7)) << 4));
            }
            #pragma unroll
            for (int ni = 0; ni < FN; ++ni) {
                int row = wn + ni * 16 + (l & 15);
                int slot = (l >> 4) + ks * 4;
                bfr[ni][ks] = *(const bf16x8*)(base + ABYTES + row * 128 + ((slot ^ (row & 7)) << 4));
            }
        }
        #pragma unroll
        for (int ks = 0; ks < 2; ++ks)
            #pragma unroll
            for (int mi = 0; mi < FM; ++mi)
                #pragma unroll
                for (int ni = 0; ni < FN; ++ni)
                    acc[mi][ni] = __builtin_amdgcn_mfma_f32_16x16x32_bf16(
                        af[mi][ks], bfr[ni][ks], acc[mi][ni], 0, 0, 0);

        asm volatile("s_waitcnt vmcnt(0)" ::: "memory");
        __syncthreads();
    }

    // epilogue: C/D frag mapping col = lane&15, row = (lane>>4)*4 + reg
    #pragma unroll
    for (int mi = 0; mi < FM; ++mi) {
        int mbase = wm + mi * 16 + (l >> 4) * 4;
        #pragma unroll
        for (int ni = 0; ni < FN; ++ni) {
            int n = n0 + wn + ni * 16 + (l & 15);
            #pragma unroll
            for (int r = 0; r < 4; ++r) {
                float v = acc[mi][ni][r];
                int mm = mbase + r;
                if (EPI == 0) C[(long)mm * ldc + n] = v + bias[n];
                if (EPI == 1) C[(long)mm * ldc + n] = v;
                if (EPI == 2) {
                    v = tanhf(v);
                    split_bf16(v, Cbh + (long)mm * ldcb + n, Cbl + (long)mm * ldcb + n);
                    C2[(long)mm * ldc2 + n] = v;
                    if (C3) C3[(long)mm * H_ + n] = v;
                }
            }
        }
    }
}

// --------------------------- LSTM cell + next-x split ----------------------
__device__ __forceinline__ float sigmoidf_(float x) { return 1.f / (1.f + expf(-x)); }

__global__ __launch_bounds__(256)
void cell_cvtx_k(const float* __restrict__ gates, const float* __restrict__ cprev,
                 float* __restrict__ cy,
                 __hip_bfloat16* __restrict__ AoBh, __hip_bfloat16* __restrict__ AoBl,
                 float* __restrict__ cf,
                 const float* __restrict__ xnext,  // input + (t+1)*D, null at last step
                 __hip_bfloat16* __restrict__ xh, __hip_bfloat16* __restrict__ xl)
{
    int bid = blockIdx.x;
    if (bid < 512) {
        int idx = bid * 256 + threadIdx.x;          // over B*H
        int b = idx >> 10, j = idx & 1023;
        const float* g = gates + ((size_t)b << 12);
        float ig = sigmoidf_(g[j]);
        float fg = sigmoidf_(g[1024 + j]);
        float gg = tanhf(g[2048 + j]);
        float og = sigmoidf_(g[3072 + j]);
        float c = fg * cprev[idx] + ig * gg;
        float h = og * tanhf(c);
        cy[idx] = c;
        split_bf16(h, AoBh + (size_t)b * 2048 + 1024 + j, AoBl + (size_t)b * 2048 + 1024 + j);
        if (cf) cf[idx] = c;
    } else if (xnext) {
        cvtx_body((bid - 512) * 256 + threadIdx.x, xnext, xh, xl);
    }
}

// --------------------------- fused online-softmax attention ----------------
__global__ __launch_bounds__(256)
void attn_k(const float* __restrict__ ctx, const float* __restrict__ q,
            const void* __restrict__ maskp, const int* __restrict__ mflag,
            __hip_bfloat16* __restrict__ AoBh, __hip_bfloat16* __restrict__ AoBl)
{
    constexpr int L = T_, H = H_;
    int b = blockIdx.x;
    const float* cb = ctx + (size_t)b * L * H;
    const float* qb = q + (size_t)b * H;
    int tid = threadIdx.x, l = tid & 63, w = tid >> 6;
    int mode = mflag[0];

    float rq[16];
    #pragma unroll
    for (int j = 0; j < 16; ++j) rq[j] = qb[l + j * 64];

    float m = -INFINITY, s = 0.f, acc[16] = {};
    for (int li = w; li < L; li += 4) {
        bool msk = mode ? (((const int*)maskp)[b * L + li] != 0)
                        : (((const unsigned char*)maskp)[b * L + li] != 0);
        if (msk) continue;
        const float* cr = cb + (size_t)li * H;
        float rc[16], d = 0.f;
        #pragma unroll
        for (int j = 0; j < 16; ++j) { rc[j] = cr[l + j * 64]; d += rc[j] * rq[j]; }
        #pragma unroll
        for (int off = 1; off < 64; off <<= 1) d += __shfl_xor(d, off);
        float mn = fmaxf(m, d);
        float f = expf(m - mn);
        float p = expf(d - mn);
        s = s * f + p;
        #pragma unroll
        for (int j = 0; j < 16; ++j) acc[j] = acc[j] * f + p * rc[j];
        m = mn;
    }

    __shared__ float sacc[4][H_];
    __shared__ float sms[4][2];
    #pragma unroll
    for (int j = 0; j < 16; ++j) sacc[w][l + j * 64] = acc[j];
    if (l == 0) { sms[w][0] = m; sms[w][1] = s; }
    __syncthreads();

    float M = fmaxf(fmaxf(sms[0][0], sms[1][0]), fmaxf(sms[2][0], sms[3][0]));
    float fw[4], S = 0.f;
    #pragma unroll
    for (int ww = 0; ww < 4; ++ww) { fw[ww] = expf(sms[ww][0] - M); S += fw[ww] * sms[ww][1]; }
    float inv = 1.f / S;
    for (int k = tid; k < H; k += 256) {
        float a = sacc[0][k] * fw[0] + sacc[1][k] * fw[1] + sacc[2][k] * fw[2] + sacc[3][k] * fw[3];
        split_bf16(a * inv, AoBh + (size_t)b * 2048 + k, AoBl + (size_t)b * 2048 + k);
    }
}

// --------------------------- launcher --------------------------------------
extern "C" void kernel_launch(void* const* d_in, const int* in_sizes, int n_in,
                              void* d_out, int out_size, void* d_ws, size_t ws_size,
                              hipStream_t stream)
{
    const float* input  = (const float*)d_in[0];
    const float* h0     = (const float*)d_in[1];
    const float* c0     = (const float*)d_in[2];
    const float* ctx    = (const float*)d_in[3];
    const void*  srcmask= d_in[4];
    const float* W_ih   = (const float*)d_in[5];
    const float* W_hh   = (const float*)d_in[6];
    const float* b_ih   = (const float*)d_in[7];
    const float* b_hh   = (const float*)d_in[8];
    const float* W_attn = (const float*)d_in[9];
    const float* W_out  = (const float*)d_in[10];

    constexpr int B = B_, T = T_, D = DIN, H = H_;

    // -------- workspace layout (~43 MB) --------
    float* f = (float*)d_ws;
    float* bsum  = f; f += 4 * H;
    float* cbuf  = f; f += (size_t)B * H;
    float* gates = f; f += (size_t)B * 4 * H;
    float* qb    = f; f += (size_t)B * H;
    int*   mflag = (int*)f; f += 64;
    __hip_bfloat16* p = (__hip_bfloat16*)f;
    __hip_bfloat16* Wgh = p; p += (size_t)4 * H * (D + H);
    __hip_bfloat16* Wgl = p; p += (size_t)4 * H * (D + H);
    __hip_bfloat16* Wah = p; p += (size_t)H * H;
    __hip_bfloat16* Wal = p; p += (size_t)H * H;
    __hip_bfloat16* Woh = p; p += (size_t)H * 2 * H;
    __hip_bfloat16* Wol = p; p += (size_t)H * 2 * H;
    __hip_bfloat16* hth = p; p += (size_t)B * H;       // h_tilde hi (recurrent)
    __hip_bfloat16* htl = p; p += (size_t)B * H;       // h_tilde lo
    __hip_bfloat16* AoBh = p; p += (size_t)B * 2 * H;  // [wctx | hy] hi
    __hip_bfloat16* AoBl = p; p += (size_t)B * 2 * H;  // [wctx | hy] lo
    __hip_bfloat16* xth[2], *xtl[2];
    xth[0] = p; p += (size_t)B * D;
    xtl[0] = p; p += (size_t)B * D;
    xth[1] = p; p += (size_t)B * D;
    xtl[1] = p; p += (size_t)B * D;

    float* out = (float*)d_out;
    float* hf  = out + (size_t)B * T * H;
    float* cf  = hf + (size_t)B * H;

    // -------- prep --------
    hipMemcpyAsync(cbuf, c0, (size_t)B * H * sizeof(float), hipMemcpyDeviceToDevice, stream);
    bias_sum_k<<<dim3(16), dim3(256), 0, stream>>>(b_ih, b_hh, bsum, 4 * H);
    detect_mask_k<<<dim3(1), dim3(256), 0, stream>>>((const int*)srcmask, B * T / 4, mflag);
    wg_split_k<<<dim3(4 * H * (D + H) / 256), dim3(256), 0, stream>>>(W_ih, W_hh, Wgh, Wgl);
    cvt_split_k<<<dim3(H * H / 256), dim3(256), 0, stream>>>(W_attn, Wah, Wal, H * H);
    cvt_split_k<<<dim3(H * 2 * H / 256), dim3(256), 0, stream>>>(W_out, Woh, Wol, H * 2 * H);
    cvt_split_k<<<dim3(B * H / 256), dim3(256), 0, stream>>>(h0, hth, htl, B * H);
    cvtx_k<<<dim3(B * D / 256), dim3(256), 0, stream>>>(input, xth[0], xtl[0]);

    dim3 blk(256);
    for (int t = 0; t < T; ++t) {
        int sl = t & 1, sn = sl ^ 1;
        // gates = [x_t | h_tilde] @ [W_ih|W_hh]^T + bsum   (N=4096, K=1536)
        mfma_gemm_k<64, 2, 2, 24, 0><<<dim3(64), blk, 0, stream>>>(
            xth[sl], xtl[sl], D, D,
            hth, htl, H,
            Wgh, Wgl, D + H,
            bsum,
            gates, 4 * H, nullptr, nullptr, 0, nullptr, 0, nullptr);

        // LSTM cell (-> cbuf, hy hi/lo into AoB) + split x_{t+1}
        cell_cvtx_k<<<dim3(768), blk, 0, stream>>>(
            gates, cbuf, cbuf, AoBh, AoBl, (t == T - 1) ? cf : nullptr,
            (t + 1 < T) ? input + (size_t)(t + 1) * D : nullptr, xth[sn], xtl[sn]);

        // q = hy @ W_attn^T   (N=1024, K=1024)
        mfma_gemm_k<16, 4, 1, 16, 1><<<dim3(64), blk, 0, stream>>>(
            AoBh + H, AoBl + H, 2 * H, H,
            AoBh + H, AoBl + H, 2 * H,
            Wah, Wal, H,
            nullptr,
            qb, H, nullptr, nullptr, 0, nullptr, 0, nullptr);

        // attention -> wctx hi/lo into AoB[:,0:H]
        attn_k<<<dim3(B), blk, 0, stream>>>(ctx, qb, srcmask, mflag, AoBh, AoBl);

        // h_tilde = tanh([wctx|hy] @ W_out^T)  (N=1024, K=2048)
        mfma_gemm_k<16, 4, 1, 32, 2><<<dim3(64), blk, 0, stream>>>(
            AoBh, AoBl, 2 * H, 2 * H,
            AoBh, AoBl, 2 * H,
            Woh, Wol, 2 * H,
            nullptr,
            nullptr, 0,
            hth, htl, H,
            out + (size_t)t * H, (long)T * H,
            (t == T - 1) ? hf : nullptr);
    }
}

// Round 4
// 18294.466 us; speedup vs baseline: 9.6925x; 2.4935x over previous
//
#include <hip/hip_runtime.h>
#include <hip/hip_bf16.h>
#include <math.h>

#define B_  128
#define T_  256
#define DIN 512
#define H_  1024

typedef __attribute__((ext_vector_type(8))) short bf16x8;
typedef __attribute__((ext_vector_type(4))) float f32x4;

#define GLD_LDS16(gsrc, ldst) \
  __builtin_amdgcn_global_load_lds((const __attribute__((address_space(1))) void*)(gsrc), \
                                   (__attribute__((address_space(3))) void*)(ldst), 16, 0, 0)

__device__ __forceinline__ void split_bf16(float v, __hip_bfloat16* hi, __hip_bfloat16* lo) {
    __hip_bfloat16 h = __float2bfloat16(v);
    *hi = h;
    *lo = __float2bfloat16(v - __bfloat162float(h));
}

template<int N> __device__ __forceinline__ void waitvm() {
    if constexpr (N == 0)       asm volatile("s_waitcnt vmcnt(0)" ::: "memory");
    else if constexpr (N == 10) asm volatile("s_waitcnt vmcnt(10)" ::: "memory");
    else static_assert(N == 0 || N == 10, "add vmcnt literal");
}

// --------------------------- small utility kernels -------------------------
__global__ void bias_sum_k(const float* __restrict__ a, const float* __restrict__ b,
                           float* __restrict__ o, int n) {
    int i = blockIdx.x * blockDim.x + threadIdx.x;
    if (i < n) o[i] = a[i] + b[i];
}

__global__ void detect_mask_k(const int* __restrict__ m, int nwords, int* __restrict__ flag) {
    __shared__ int bad;
    if (threadIdx.x == 0) bad = 0;
    __syncthreads();
    for (int i = threadIdx.x; i < nwords; i += blockDim.x) {
        unsigned v = (unsigned)m[i];
        if (v > 1u) bad = 1;
    }
    __syncthreads();
    if (threadIdx.x == 0) flag[0] = bad ? 0 : 1;  // 1 => int32 mask, 0 => u8 mask
}

__global__ void cvt_split_k(const float* __restrict__ s, __hip_bfloat16* __restrict__ hi,
                            __hip_bfloat16* __restrict__ lo, int n) {
    int i = blockIdx.x * 256 + threadIdx.x;
    if (i < n) split_bf16(s[i], hi + i, lo + i);
}

__global__ void wg_split_k(const float* __restrict__ Wih, const float* __restrict__ Whh,
                           __hip_bfloat16* __restrict__ Wh, __hip_bfloat16* __restrict__ Wl) {
    int i = blockIdx.x * 256 + threadIdx.x;           // over 4096*1536
    int n = i / 1536, c = i - n * 1536;
    float v = (c < DIN) ? Wih[n * DIN + c] : Whh[n * H_ + (c - DIN)];
    split_bf16(v, Wh + i, Wl + i);
}

__device__ __forceinline__ void cvtx_body(int i, const float* __restrict__ xsrc,
                                          __hip_bfloat16* __restrict__ xh,
                                          __hip_bfloat16* __restrict__ xl) {
    int b = i >> 9, c = i & 511;
    split_bf16(xsrc[(size_t)b * (T_ * DIN) + c], xh + i, xl + i);
}

__global__ void cvtx_k(const float* __restrict__ xsrc, __hip_bfloat16* __restrict__ xh,
                       __hip_bfloat16* __restrict__ xl) {
    cvtx_body(blockIdx.x * 256 + threadIdx.x, xsrc, xh, xl);
}

// --------------------------- plane-fused split-bf16 MFMA GEMM --------------
// Cpart[ksp][128][N] = (Ah+Al)[128, kslice] @ (Wh+Wl)[N, kslice]^T
// Per K-tile stages Ah,Al,Wh,Wl (BK=64) and runs 3 MFMA combos (hh, lh, hl).
// BM=128, BN=32, 256 thr (2x2 waves), 3-buffer LDS, counted-vmcnt 2-deep
// prefetch with raw s_barrier (loads stay in flight across barriers).
// ksp = blockIdx.y, kbase = ksp * NT * 64.
template<int NT>
__global__ __launch_bounds__(256)
void mfma_gemm_k(const __hip_bfloat16* __restrict__ A1h, const __hip_bfloat16* __restrict__ A1l,
                 long lda1, int K1,
                 const __hip_bfloat16* __restrict__ A2h, const __hip_bfloat16* __restrict__ A2l,
                 long lda2,
                 const __hip_bfloat16* __restrict__ Wh, const __hip_bfloat16* __restrict__ Wl,
                 long ldw,
                 float* __restrict__ Cpart, long ldc, long pstride)
{
    constexpr int APL = 128 * 64 * 2;      // one A plane: 16 KB
    constexpr int BPL = 32 * 64 * 2;       // one B plane: 4 KB
    constexpr int BUFB = 2 * APL + 2 * BPL; // 40 KB
    __shared__ __attribute__((aligned(16))) char lds[3 * BUFB];   // 120 KB

    const int tid = threadIdx.x;
    const int l = tid & 63, w = tid >> 6;
    const int n0 = blockIdx.x * 32;
    const int kbase = blockIdx.y * (NT * 64);
    const int wm = (w >> 1) * 64, wn = (w & 1) * 16;

    auto stage = [&](int buf, int kt) {
        char* base = lds + buf * BUFB;
        const int kb = kbase + kt * 64;
        #pragma unroll
        for (int p = 0; p < 2; ++p) {
            const __hip_bfloat16* A1 = p ? A1l : A1h;
            const __hip_bfloat16* A2 = p ? A2l : A2h;
            #pragma unroll
            for (int j = 0; j < 4; ++j) {                 // A plane: 4 gld/thread
                int c = j * 256 + tid;
                int row = c >> 3, slot = c & 7;
                int e = kb + ((slot ^ (row & 7)) << 3);
                const __hip_bfloat16* src = (e < K1) ? (A1 + (long)row * lda1 + e)
                                                     : (A2 + (long)row * lda2 + (e - K1));
                GLD_LDS16(src, base + p * APL + ((j * 256 + (tid & 192)) << 4));
            }
            {                                             // B plane: 1 gld/thread
                int row = tid >> 3, slot = tid & 7;
                int e = kb + ((slot ^ (row & 7)) << 3);
                const __hip_bfloat16* src = (p ? Wl : Wh) + (long)(n0 + row) * ldw + e;
                GLD_LDS16(src, base + 2 * APL + p * BPL + ((tid & 192) << 4));
            }
        }
    };  // 10 gld instructions per thread per stage

    f32x4 acc[4] = {};

    stage(0, 0);
    if (NT > 1) stage(1, 1);

    for (int kt = 0; kt < NT; ++kt) {
        if (kt + 1 < NT) waitvm<10>(); else waitvm<0>();
        __builtin_amdgcn_s_barrier();
        __builtin_amdgcn_sched_barrier(0);
        if (kt + 2 < NT) stage((kt + 2) % 3, kt + 2);

        const char* base = lds + (kt % 3) * BUFB;
        #pragma unroll
        for (int ks = 0; ks < 2; ++ks) {
            bf16x8 afh[4], afl[4], bh, bl;
            #pragma unroll
            for (int mi = 0; mi < 4; ++mi) {
                int row = wm + mi * 16 + (l & 15);
                int slot = (l >> 4) + ks * 4;
                int off = row * 128 + ((slot ^ (row & 7)) << 4);
                afh[mi] = *(const bf16x8*)(base + off);
                afl[mi] = *(const bf16x8*)(base + APL + off);
            }
            {
                int row = wn + (l & 15);
                int slot = (l >> 4) + ks * 4;
                int off = row * 128 + ((slot ^ (row & 7)) << 4);
                bh = *(const bf16x8*)(base + 2 * APL + off);
                bl = *(const bf16x8*)(base + 2 * APL + BPL + off);
            }
            #pragma unroll
            for (int mi = 0; mi < 4; ++mi) {
                acc[mi] = __builtin_amdgcn_mfma_f32_16x16x32_bf16(afh[mi], bh, acc[mi], 0, 0, 0);
                acc[mi] = __builtin_amdgcn_mfma_f32_16x16x32_bf16(afl[mi], bh, acc[mi], 0, 0, 0);
                acc[mi] = __builtin_amdgcn_mfma_f32_16x16x32_bf16(afh[mi], bl, acc[mi], 0, 0, 0);
            }
        }
    }

    float* Cb = Cpart + (long)blockIdx.y * pstride;
    const int n = n0 + wn + (l & 15);
    #pragma unroll
    for (int mi = 0; mi < 4; ++mi) {
        int mbase = wm + mi * 16 + (l >> 4) * 4;
        #pragma unroll
        for (int r = 0; r < 4; ++r)
            Cb[(long)(mbase + r) * ldc + n] = acc[mi][r];
    }
}

// --------------------------- LSTM cell (+ next-x split) --------------------
__device__ __forceinline__ float sigmoidf_(float x) { return 1.f / (1.f + expf(-x)); }

__global__ __launch_bounds__(256)
void cell_cvtx_k(const float* __restrict__ gpart,   // [2][128][4096]
                 const float* __restrict__ bsum,
                 const float* __restrict__ cprev, float* __restrict__ cy,
                 __hip_bfloat16* __restrict__ AoBh, __hip_bfloat16* __restrict__ AoBl,
                 float* __restrict__ cf,
                 const float* __restrict__ xnext,
                 __hip_bfloat16* __restrict__ xh, __hip_bfloat16* __restrict__ xl)
{
    int bid = blockIdx.x;
    if (bid < 512) {
        int idx = bid * 256 + threadIdx.x;          // over B*H
        int b = idx >> 10, j = idx & 1023;
        const float* g0 = gpart + ((size_t)b << 12);
        const float* g1 = g0 + (size_t)128 * 4096;
        float ig = sigmoidf_(g0[j]        + g1[j]        + bsum[j]);
        float fg = sigmoidf_(g0[1024 + j] + g1[1024 + j] + bsum[1024 + j]);
        float gg = tanhf    (g0[2048 + j] + g1[2048 + j] + bsum[2048 + j]);
        float og = sigmoidf_(g0[3072 + j] + g1[3072 + j] + bsum[3072 + j]);
        float c = fg * cprev[idx] + ig * gg;
        float h = og * tanhf(c);
        cy[idx] = c;
        split_bf16(h, AoBh + (size_t)b * 2048 + 1024 + j, AoBl + (size_t)b * 2048 + 1024 + j);
        if (cf) cf[idx] = c;
    } else if (xnext) {
        cvtx_body((bid - 512) * 256 + threadIdx.x, xnext, xh, xl);
    }
}

// --------------------------- fused online-softmax attention ----------------
__global__ __launch_bounds__(256)
void attn_k(const float* __restrict__ ctx, const float* __restrict__ qpart, // [4][128][1024]
            const void* __restrict__ maskp, const int* __restrict__ mflag,
            __hip_bfloat16* __restrict__ AoBh, __hip_bfloat16* __restrict__ AoBl)
{
    constexpr int L = T_, H = H_;
    int b = blockIdx.x;
    const float* cb = ctx + (size_t)b * L * H;
    int tid = threadIdx.x, l = tid & 63, w = tid >> 6;
    int mode = mflag[0];

    float rq[16];
    #pragma unroll
    for (int j = 0; j < 16; ++j) {
        size_t o = (size_t)b * H + l + j * 64;
        rq[j] = qpart[o] + qpart[o + 131072] + qpart[o + 262144] + qpart[o + 393216];
    }

    float m = -INFINITY, s = 0.f, acc[16] = {};
    for (int li = w; li < L; li += 4) {
        bool msk = mode ? (((const int*)maskp)[b * L + li] != 0)
                        : (((const unsigned char*)maskp)[b * L + li] != 0);
        if (msk) continue;
        const float* cr = cb + (size_t)li * H;
        float rc[16], d = 0.f;
        #pragma unroll
        for (int j = 0; j < 16; ++j) { rc[j] = cr[l + j * 64]; d += rc[j] * rq[j]; }
        #pragma unroll
        for (int off = 1; off < 64; off <<= 1) d += __shfl_xor(d, off);
        float mn = fmaxf(m, d);
        float f = expf(m - mn);
        float p = expf(d - mn);
        s = s * f + p;
        #pragma unroll
        for (int j = 0; j < 16; ++j) acc[j] = acc[j] * f + p * rc[j];
        m = mn;
    }

    __shared__ float sacc[4][H_];
    __shared__ float sms[4][2];
    #pragma unroll
    for (int j = 0; j < 16; ++j) sacc[w][l + j * 64] = acc[j];
    if (l == 0) { sms[w][0] = m; sms[w][1] = s; }
    __syncthreads();

    float M = fmaxf(fmaxf(sms[0][0], sms[1][0]), fmaxf(sms[2][0], sms[3][0]));
    float fw[4], S = 0.f;
    #pragma unroll
    for (int ww = 0; ww < 4; ++ww) { fw[ww] = expf(sms[ww][0] - M); S += fw[ww] * sms[ww][1]; }
    float inv = 1.f / S;
    for (int k = tid; k < H; k += 256) {
        float a = sacc[0][k] * fw[0] + sacc[1][k] * fw[1] + sacc[2][k] * fw[2] + sacc[3][k] * fw[3];
        split_bf16(a * inv, AoBh + (size_t)b * 2048 + k, AoBl + (size_t)b * 2048 + k);
    }
}

// --------------------------- out-partial reduce + tanh + split -------------
__global__ __launch_bounds__(256)
void outred_k(const float* __restrict__ opart,      // [4][128][1024]
              __hip_bfloat16* __restrict__ hth, __hip_bfloat16* __restrict__ htl,
              float* __restrict__ outp,             // out + t*H
              float* __restrict__ hf)
{
    int idx = blockIdx.x * 256 + threadIdx.x;       // over B*H
    int b = idx >> 10, j = idx & 1023;
    float v = opart[idx] + opart[idx + 131072] + opart[idx + 262144] + opart[idx + 393216];
    v = tanhf(v);
    split_bf16(v, hth + idx, htl + idx);
    outp[(size_t)b * (T_ * H_) + j] = v;
    if (hf) hf[idx] = v;
}

// --------------------------- launcher --------------------------------------
extern "C" void kernel_launch(void* const* d_in, const int* in_sizes, int n_in,
                              void* d_out, int out_size, void* d_ws, size_t ws_size,
                              hipStream_t stream)
{
    const float* input  = (const float*)d_in[0];
    const float* h0     = (const float*)d_in[1];
    const float* c0     = (const float*)d_in[2];
    const float* ctx    = (const float*)d_in[3];
    const void*  srcmask= d_in[4];
    const float* W_ih   = (const float*)d_in[5];
    const float* W_hh   = (const float*)d_in[6];
    const float* b_ih   = (const float*)d_in[7];
    const float* b_hh   = (const float*)d_in[8];
    const float* W_attn = (const float*)d_in[9];
    const float* W_out  = (const float*)d_in[10];

    constexpr int B = B_, T = T_, D = DIN, H = H_;

    // -------- workspace --------
    float* f = (float*)d_ws;
    float* bsum  = f; f += 4 * H;
    float* cbuf  = f; f += (size_t)B * H;
    float* gpart = f; f += (size_t)2 * B * 4 * H;
    float* qpart = f; f += (size_t)4 * B * H;
    float* opart = f; f += (size_t)4 * B * H;
    int*   mflag = (int*)f; f += 64;
    __hip_bfloat16* p = (__hip_bfloat16*)f;
    __hip_bfloat16* Wgh = p; p += (size_t)4 * H * (D + H);
    __hip_bfloat16* Wgl = p; p += (size_t)4 * H * (D + H);
    __hip_bfloat16* Wah = p; p += (size_t)H * H;
    __hip_bfloat16* Wal = p; p += (size_t)H * H;
    __hip_bfloat16* Woh = p; p += (size_t)H * 2 * H;
    __hip_bfloat16* Wol = p; p += (size_t)H * 2 * H;
    __hip_bfloat16* hth = p; p += (size_t)B * H;
    __hip_bfloat16* htl = p; p += (size_t)B * H;
    __hip_bfloat16* AoBh = p; p += (size_t)B * 2 * H;
    __hip_bfloat16* AoBl = p; p += (size_t)B * 2 * H;
    __hip_bfloat16* xth[2], *xtl[2];
    xth[0] = p; p += (size_t)B * D;
    xtl[0] = p; p += (size_t)B * D;
    xth[1] = p; p += (size_t)B * D;
    xtl[1] = p; p += (size_t)B * D;

    float* out = (float*)d_out;
    float* hf  = out + (size_t)B * T * H;
    float* cf  = hf + (size_t)B * H;

    // -------- prep --------
    hipMemcpyAsync(cbuf, c0, (size_t)B * H * sizeof(float), hipMemcpyDeviceToDevice, stream);
    bias_sum_k<<<dim3(16), dim3(256), 0, stream>>>(b_ih, b_hh, bsum, 4 * H);
    detect_mask_k<<<dim3(1), dim3(256), 0, stream>>>((const int*)srcmask, B * T / 4, mflag);
    wg_split_k<<<dim3(4 * H * (D + H) / 256), dim3(256), 0, stream>>>(W_ih, W_hh, Wgh, Wgl);
    cvt_split_k<<<dim3(H * H / 256), dim3(256), 0, stream>>>(W_attn, Wah, Wal, H * H);
    cvt_split_k<<<dim3(H * 2 * H / 256), dim3(256), 0, stream>>>(W_out, Woh, Wol, H * 2 * H);
    cvt_split_k<<<dim3(B * H / 256), dim3(256), 0, stream>>>(h0, hth, htl, B * H);
    cvtx_k<<<dim3(B * D / 256), dim3(256), 0, stream>>>(input, xth[0], xtl[0]);

    dim3 blk(256);
    for (int t = 0; t < T; ++t) {
        int sl = t & 1, sn = sl ^ 1;

        // gates partials: [x_t | h_tilde] @ [W_ih|W_hh]^T   K=1536, Ksplit=2
        mfma_gemm_k<12><<<dim3(128, 2), blk, 0, stream>>>(
            xth[sl], xtl[sl], D, D,
            hth, htl, H,
            Wgh, Wgl, D + H,
            gpart, 4 * H, (long)B * 4 * H);

        // cell (reduce partials + bias) + split x_{t+1}
        cell_cvtx_k<<<dim3(768), blk, 0, stream>>>(
            gpart, bsum, cbuf, cbuf, AoBh, AoBl, (t == T - 1) ? cf : nullptr,
            (t + 1 < T) ? input + (size_t)(t + 1) * D : nullptr, xth[sn], xtl[sn]);

        // q partials: hy @ W_attn^T   K=1024, Ksplit=4
        mfma_gemm_k<4><<<dim3(32, 4), blk, 0, stream>>>(
            AoBh + H, AoBl + H, 2 * H, 2 * H,
            AoBh + H, AoBl + H, 2 * H,
            Wah, Wal, H,
            qpart, H, (long)B * H);

        // attention (reduces q partials) -> wctx into AoB[:,0:H]
        attn_k<<<dim3(B), blk, 0, stream>>>(ctx, qpart, srcmask, mflag, AoBh, AoBl);

        // out partials: [wctx|hy] @ W_out^T   K=2048, Ksplit=4
        mfma_gemm_k<8><<<dim3(32, 4), blk, 0, stream>>>(
            AoBh, AoBl, 2 * H, 2 * H,
            AoBh, AoBl, 2 * H,
            Woh, Wol, 2 * H,
            opart, H, (long)B * H);

        // reduce + tanh + split -> hth/htl, output slice, (h_f)
        outred_k<<<dim3(512), blk, 0, stream>>>(
            opart, hth, htl, out + (size_t)t * H, (t == T - 1) ? hf : nullptr);
    }
}